// Round 13
// baseline (315.928 us; speedup 1.0000x reference)
//
#include <hip/hip_runtime.h>
#include <hip/hip_bf16.h>
#include <hip/hip_fp16.h>
#include <cstdint>
#include <cstddef>

#define HID 256
#define EMBD 128
#define FIN 5
#define NBLK 256   // histogram/placement blocks
#define VRB 32     // v-reduce blocks

typedef __attribute__((ext_vector_type(8))) short bf16x8;
typedef __attribute__((ext_vector_type(4))) float f32x4;

__device__ __forceinline__ unsigned short f2bf(float f) {
  unsigned int u = __float_as_uint(f);
  u += 0x7FFFu + ((u >> 16) & 1u);   // RNE
  return (unsigned short)(u >> 16);
}
__device__ __forceinline__ float bflo(unsigned int u) { return __uint_as_float(u << 16); }
__device__ __forceinline__ float bfhi(unsigned int u) { return __uint_as_float(u & 0xFFFF0000u); }
__device__ __forceinline__ unsigned int pack2bf(float a, float b) {
  return ((unsigned int)f2bf(b) << 16) | (unsigned int)f2bf(a);
}

// ---------------- K1: dual LDS histogram (dst & src buckets) + W2 -> fragment order ------
__global__ __launch_bounds__(256) void k_hist(const int* __restrict__ ei,
                                              const float* __restrict__ W2,
                                              int* __restrict__ h2dD,
                                              int* __restrict__ h2dS,
                                              unsigned short* __restrict__ W2f,
                                              int E, int NB, int per) {
  int b = blockIdx.x, t = threadIdx.x;
  if (b >= NBLK) {  // W2 pack blocks: b-NBLK = n (col), t = k
    int n = b - NBLK;
    size_t off = ((((size_t)(n >> 4) * 8 + (t >> 5)) * 64) +
                  (size_t)((t >> 3) & 3) * 16 + (n & 15)) * 8 + (t & 7);
    W2f[off] = f2bf(W2[(size_t)t * HID + n]);
    return;
  }
  extern __shared__ int hsh[];  // 2*NB ints
  int* hD = hsh;
  int* hS = hsh + NB;
  for (int j = t; j < 2 * NB; j += 256) hsh[j] = 0;
  __syncthreads();
  int lo = b * per, hi = min(E, lo + per);
  for (int e = lo + t; e < hi; e += 256) {
    int s = ei[e];
    int d = ei[(size_t)E + e];
    atomicAdd(&hD[d >> 6], 1);
    atomicAdd(&hS[s >> 6], 1);
  }
  __syncthreads();
  for (int j = t; j < NB; j += 256) {
    h2dD[(size_t)b * NB + j] = hD[j];
    h2dS[(size_t)b * NB + j] = hS[j];
  }
}

// ---------------- K2: per-bucket exclusive scan over blocks ----------------
__global__ __launch_bounds__(256) void k_bred(int* __restrict__ h2dD,
                                              int* __restrict__ h2dS,
                                              int* __restrict__ btot, int NB) {
  __shared__ int sh[NBLK];
  int bb = blockIdx.x, t = threadIdx.x;
  int* arr = (bb < NB) ? h2dD : h2dS;
  int b = (bb < NB) ? bb : bb - NB;
  int v = arr[(size_t)t * NB + b];
  sh[t] = v;
  __syncthreads();
  for (int off = 1; off < 256; off <<= 1) {
    int u = (t >= off) ? sh[t - off] : 0;
    __syncthreads();
    sh[t] += u;
    __syncthreads();
  }
  arr[(size_t)t * NB + b] = sh[t] - v;   // exclusive over blocks
  if (t == 255) btot[bb] = sh[255];
}

// ---------------- K3: scan bucket totals -> bucket starts ----------------
__global__ __launch_bounds__(256) void k_bscan(const int* __restrict__ btot,
                                               int* __restrict__ bsD,
                                               int* __restrict__ bsS,
                                               int* __restrict__ row,
                                               int E, int NB, int N) {
  __shared__ int sh[256];
  __shared__ int carrysh;
  int t = threadIdx.x;
  for (int which = 0; which < 2; which++) {
    const int* src = btot + (size_t)which * NB;
    int* dst = which ? bsS : bsD;
    if (t == 0) carrysh = 0;
    __syncthreads();
    int nch = (NB + 255) / 256;
    for (int c = 0; c < nch; c++) {
      int i = c * 256 + t;
      int v = (i < NB) ? src[i] : 0;
      sh[t] = v;
      __syncthreads();
      for (int off = 1; off < 256; off <<= 1) {
        int u = (t >= off) ? sh[t - off] : 0;
        __syncthreads();
        sh[t] += u;
        __syncthreads();
      }
      int carry = carrysh;
      if (i < NB) dst[i] = carry + sh[t] - v;
      __syncthreads();
      if (t == 255) carrysh = carry + sh[255];
      __syncthreads();
    }
    if (t == 0) dst[NB] = E;
    __syncthreads();
  }
  if (t == 0) row[N] = E;
}

// ---------------- K4: placement into bucket-sorted edge arrays (LDS counters only) --------
__global__ __launch_bounds__(256) void k_place(const int* __restrict__ ei,
                                               const int* __restrict__ h2dD,
                                               const int* __restrict__ h2dS,
                                               const int* __restrict__ bsD,
                                               const int* __restrict__ bsS,
                                               unsigned int* __restrict__ seD,
                                               unsigned int* __restrict__ seS,
                                               int E, int NB, int per) {
  extern __shared__ int osh[];  // 2*NB ints
  int* oD = osh;
  int* oS = osh + NB;
  int b = blockIdx.x, t = threadIdx.x;
  for (int j = t; j < NB; j += 256) {
    oD[j] = bsD[j] + h2dD[(size_t)b * NB + j];
    oS[j] = bsS[j] + h2dS[(size_t)b * NB + j];
  }
  __syncthreads();
  int lo = b * per, hi = min(E, lo + per);
  for (int e = lo + t; e < hi; e += 256) {
    int s = ei[e];
    int d = ei[(size_t)E + e];
    int pd = atomicAdd(&oD[d >> 6], 1);
    seD[pd] = (unsigned int)s | ((unsigned int)(d & 63) << 20);
    int ps = atomicAdd(&oS[s >> 6], 1);
    seS[ps] = (unsigned int)d | ((unsigned int)(s & 63) << 20);
  }
}

// ---------------- K5: per-bucket dst CSR finalize: csr, row + inv/xi/gfeat ----------------
__global__ __launch_bounds__(256) void k_csrd(const unsigned int* __restrict__ seD,
                                              const int* __restrict__ bsD,
                                              const float* __restrict__ x,
                                              int* __restrict__ csr,
                                              int* __restrict__ row,
                                              float* __restrict__ inv,
                                              uint4* __restrict__ xi,
                                              float* __restrict__ gpart,
                                              int NB, int N) {
  __shared__ int cnt[64], sc[64], ofs[64];
  int b = blockIdx.x, t = threadIdx.x;
  if (t < 64) cnt[t] = 0;
  __syncthreads();
  int lo = bsD[b], hi = bsD[b + 1];
  for (int k = lo + t; k < hi; k += 256) atomicAdd(&cnt[seD[k] >> 20], 1);
  __syncthreads();
  if (t < 64) sc[t] = cnt[t];
  __syncthreads();
  for (int off = 1; off < 64; off <<= 1) {
    int u = (t < 64 && t >= off) ? sc[t - off] : 0;
    __syncthreads();
    if (t < 64) sc[t] += u;
    __syncthreads();
  }
  if (t < 64) {
    int ex = sc[t] - cnt[t];
    ofs[t] = ex;
    int node = b * 64 + t;
    float s2 = 0.f, s3 = 0.f, s4 = 0.f, c0 = 0.f, sl = 0.f, sm = 0.f;
    if (node < N) {
      row[node] = lo + ex;
      float iv = rsqrtf((float)cnt[t] + 1.0f);
      inv[node] = iv;
      float x0 = x[(size_t)node * 5 + 0];
      float x1 = x[(size_t)node * 5 + 1];
      float x2 = x[(size_t)node * 5 + 2];
      float x3 = x[(size_t)node * 5 + 3];
      float x4 = x[(size_t)node * 5 + 4];
      uint4 o;
      o.x = pack2bf(x0 * iv, x1 * iv);
      o.y = pack2bf(x2 * iv, x3 * iv);
      o.z = pack2bf(x4 * iv, 0.f);
      o.w = 0u;
      xi[node] = o;
      s2 = x2; s3 = x3; s4 = x4;
      if (x2 == 1.0f) { c0 = 1.f; sl = x0; sm = x1; }
    }
    #pragma unroll
    for (int off = 32; off > 0; off >>= 1) {
      s2 += __shfl_down(s2, off);
      s3 += __shfl_down(s3, off);
      s4 += __shfl_down(s4, off);
      c0 += __shfl_down(c0, off);
      sl += __shfl_down(sl, off);
      sm += __shfl_down(sm, off);
    }
    if (t == 0) {
      gpart[(size_t)b * 8 + 0] = s2;
      gpart[(size_t)b * 8 + 1] = s3;
      gpart[(size_t)b * 8 + 2] = s4;
      gpart[(size_t)b * 8 + 3] = c0;
      gpart[(size_t)b * 8 + 4] = sl;
      gpart[(size_t)b * 8 + 5] = sm;
      gpart[(size_t)b * 8 + 6] = 0.f;
      gpart[(size_t)b * 8 + 7] = 0.f;
    }
  }
  __syncthreads();
  for (int k = lo + t; k < hi; k += 256) {
    unsigned int v = seD[k];
    int p = atomicAdd(&ofs[v >> 20], 1);
    csr[lo + p] = (int)(v & 0xFFFFFu);
  }
}

// ---------------- K7: per-bucket src pass: w_raw[s] = sum inv[dst] (LDS only) ----------
__global__ __launch_bounds__(256) void k_csrs(const unsigned int* __restrict__ seS,
                                              const int* __restrict__ bsS,
                                              const float* __restrict__ inv,
                                              float* __restrict__ w, int NB, int N) {
  __shared__ float wa[64];
  int b = blockIdx.x, t = threadIdx.x;
  if (t < 64) wa[t] = 0.f;
  __syncthreads();
  int lo = bsS[b], hi = bsS[b + 1];
  for (int k = lo + t; k < hi; k += 256) {
    unsigned int v = seS[k];
    atomicAdd(&wa[v >> 20], inv[v & 0xFFFFFu]);
  }
  __syncthreads();
  if (t < 64) {
    int node = b * 64 + t;
    if (node < N) w[node] = wa[t];
  }
}

// ---------------- K8: thread-per-node xi gather -> generator vec g = (a0..a4, inv) ------
__global__ __launch_bounds__(256) void k_gvec(const uint4* __restrict__ xi,
                                              const int* __restrict__ row,
                                              const int* __restrict__ csr,
                                              const float* __restrict__ inv,
                                              float4* __restrict__ g,
                                              float* __restrict__ w, int N) {
  int n = blockIdx.x * 256 + threadIdx.x;
  if (n >= N) return;
  float invd = inv[n];
  int start = row[n], end = row[n + 1];
  float a0 = 0.f, a1 = 0.f, a2 = 0.f, a3 = 0.f, a4 = 0.f;
  for (int e = start; e < end; e++) {
    uint4 vx = xi[csr[e]];
    a0 += bflo(vx.x); a1 += bfhi(vx.x);
    a2 += bflo(vx.y); a3 += bfhi(vx.y);
    a4 += bflo(vx.z);
  }
  uint4 vs = xi[n];
  a0 += bflo(vs.x); a1 += bfhi(vs.x);
  a2 += bflo(vs.y); a3 += bfhi(vs.y);
  a4 += bflo(vs.z);
  a0 *= invd; a1 *= invd; a2 *= invd; a3 *= invd; a4 *= invd;
  w[n] = invd * w[n] + invd * invd;  // finalize pooling weight
  float4 ga = {a0, a1, a2, a3};
  float4 gb = {a4, invd, 0.f, 0.f};
  g[(size_t)2 * n] = ga;
  g[(size_t)2 * n + 1] = gb;
}

// ---------------- K9: recompute-gather: Z[d] = inv_d * sum_s inv_s*relu(W1^T a_s + b1) --
// wave per node; lane owns cols 4l..4l+3 (W1 fragment in regs); 32B broadcast per edge.
__global__ __launch_bounds__(256) void k_agg(const int* __restrict__ row,
                                             const int* __restrict__ csr,
                                             const float* __restrict__ inv,
                                             const float4* __restrict__ g,
                                             const float* __restrict__ W1,
                                             const float* __restrict__ b1,
                                             unsigned short* __restrict__ Zb, int N) {
  int wv = threadIdx.x >> 6, l = threadIdx.x & 63;
  int d = blockIdx.x * 4 + wv;
  int c0 = l * 4;
  if (d >= N) {
    uint2 z = {0u, 0u};
    *(uint2*)(Zb + (size_t)d * HID + c0) = z;
    return;
  }
  float4 w0 = *(const float4*)(W1 + 0 * HID + c0);
  float4 w1 = *(const float4*)(W1 + 1 * HID + c0);
  float4 w2 = *(const float4*)(W1 + 2 * HID + c0);
  float4 w3 = *(const float4*)(W1 + 3 * HID + c0);
  float4 w4 = *(const float4*)(W1 + 4 * HID + c0);
  float4 bb = *(const float4*)(b1 + c0);
  float4 acc = {0.f, 0.f, 0.f, 0.f};

#define ACCG(ga, gb)                                                          \
  {                                                                           \
    float hx = fmaf(ga.x, w0.x, bb.x);                                        \
    float hy = fmaf(ga.x, w0.y, bb.y);                                        \
    float hz = fmaf(ga.x, w0.z, bb.z);                                        \
    float hw = fmaf(ga.x, w0.w, bb.w);                                        \
    hx = fmaf(ga.y, w1.x, hx); hy = fmaf(ga.y, w1.y, hy);                     \
    hz = fmaf(ga.y, w1.z, hz); hw = fmaf(ga.y, w1.w, hw);                     \
    hx = fmaf(ga.z, w2.x, hx); hy = fmaf(ga.z, w2.y, hy);                     \
    hz = fmaf(ga.z, w2.z, hz); hw = fmaf(ga.z, w2.w, hw);                     \
    hx = fmaf(ga.w, w3.x, hx); hy = fmaf(ga.w, w3.y, hy);                     \
    hz = fmaf(ga.w, w3.z, hz); hw = fmaf(ga.w, w3.w, hw);                     \
    hx = fmaf(gb.x, w4.x, hx); hy = fmaf(gb.x, w4.y, hy);                     \
    hz = fmaf(gb.x, w4.z, hz); hw = fmaf(gb.x, w4.w, hw);                     \
    float iv = gb.y;                                                          \
    acc.x = fmaf(iv, fmaxf(hx, 0.f), acc.x);                                  \
    acc.y = fmaf(iv, fmaxf(hy, 0.f), acc.y);                                  \
    acc.z = fmaf(iv, fmaxf(hz, 0.f), acc.z);                                  \
    acc.w = fmaf(iv, fmaxf(hw, 0.f), acc.w);                                  \
  }

  int start = row[d], end = row[d + 1];
  int e = start;
  for (; e + 1 < end; e += 2) {
    int s0 = csr[e], s1 = csr[e + 1];
    float4 ga0 = g[(size_t)2 * s0], gb0 = g[(size_t)2 * s0 + 1];
    float4 ga1 = g[(size_t)2 * s1], gb1 = g[(size_t)2 * s1 + 1];
    ACCG(ga0, gb0);
    ACCG(ga1, gb1);
  }
  if (e < end) {
    int s0 = csr[e];
    float4 ga0 = g[(size_t)2 * s0], gb0 = g[(size_t)2 * s0 + 1];
    ACCG(ga0, gb0);
  }
  {  // self-loop
    float4 ga = g[(size_t)2 * d], gb = g[(size_t)2 * d + 1];
    ACCG(ga, gb);
  }
#undef ACCG
  float invd = inv[d];
  uint2 o;
  o.x = pack2bf(acc.x * invd, acc.y * invd);
  o.y = pack2bf(acc.z * invd, acc.w * invd);
  *(uint2*)(Zb + (size_t)d * HID + c0) = o;
}

// ---------------- K10: MFMA GEMM: H2 = relu(Z @ W2 + b2); part[blk] = H2^T w -----------
__global__ __launch_bounds__(256, 2) void k_gemm2(const unsigned short* __restrict__ Zb,
                                                  const float* __restrict__ w,
                                                  const unsigned short* __restrict__ W2f,
                                                  const float* __restrict__ b2,
                                                  float* __restrict__ part, int N) {
  __shared__ unsigned short Bsh[16384];  // 32 KB: 4 col-tiles x 8 kb x 64 lanes x 8
  __shared__ float vsh[4][HID];
  int t = threadIdx.x;
  int wv = t >> 6, l = t & 63;
  int lo = l & 15, hi = l >> 4;
  int row0 = blockIdx.x * 256 + wv * 64;

  bf16x8 a[4][8];
  #pragma unroll
  for (int rt = 0; rt < 4; rt++) {
    const unsigned short* zrow = Zb + (size_t)(row0 + rt * 16 + lo) * HID + hi * 8;
    #pragma unroll
    for (int kb = 0; kb < 8; kb++)
      a[rt][kb] = *reinterpret_cast<const bf16x8*>(zrow + kb * 32);
  }
  float w4[4][4];
  #pragma unroll
  for (int rt = 0; rt < 4; rt++)
    #pragma unroll
    for (int i = 0; i < 4; i++) {
      int gr = row0 + rt * 16 + hi * 4 + i;
      w4[rt][i] = (gr < N) ? w[gr] : 0.f;
    }

  for (int c = 0; c < 4; c++) {  // chunk of 4 col-tiles
    {
      const uint4* src = (const uint4*)(W2f + (size_t)c * 16384);
      uint4* dst = (uint4*)Bsh;
      #pragma unroll
      for (int i = 0; i < 8; i++) dst[t + i * 256] = src[t + i * 256];
    }
    __syncthreads();
    #pragma unroll
    for (int cp = 0; cp < 2; cp++) {
      int ct2 = cp * 2;
      f32x4 acc[2][4];
      #pragma unroll
      for (int u = 0; u < 2; u++)
        #pragma unroll
        for (int rt = 0; rt < 4; rt++) acc[u][rt] = (f32x4){0.f, 0.f, 0.f, 0.f};
      #pragma unroll
      for (int kb = 0; kb < 8; kb++) {
        bf16x8 b0 = *reinterpret_cast<const bf16x8*>(Bsh + ((ct2 * 8 + kb) * 64 + l) * 8);
        bf16x8 b1 = *reinterpret_cast<const bf16x8*>(Bsh + (((ct2 + 1) * 8 + kb) * 64 + l) * 8);
        #pragma unroll
        for (int rt = 0; rt < 4; rt++) {
          acc[0][rt] = __builtin_amdgcn_mfma_f32_16x16x32_bf16(a[rt][kb], b0, acc[0][rt], 0, 0, 0);
          acc[1][rt] = __builtin_amdgcn_mfma_f32_16x16x32_bf16(a[rt][kb], b1, acc[1][rt], 0, 0, 0);
        }
      }
      #pragma unroll
      for (int u = 0; u < 2; u++) {
        int col = (c * 4 + ct2 + u) * 16 + lo;
        float bc = b2[col];
        float p = 0.f;
        #pragma unroll
        for (int rt = 0; rt < 4; rt++)
          #pragma unroll
          for (int i = 0; i < 4; i++)
            p = fmaf(w4[rt][i], fmaxf(acc[u][rt][i] + bc, 0.f), p);
        p += __shfl_xor(p, 16);
        p += __shfl_xor(p, 32);
        if (hi == 0) vsh[wv][col] = p;
      }
    }
    __syncthreads();
  }
  float s = vsh[0][t] + vsh[1][t] + vsh[2][t] + vsh[3][t];
  part[(size_t)blockIdx.x * HID + t] = s;
}

// ---------------- K10b: parallel partial reduce part[P][256] -> part2[VRB][256] --------
__global__ __launch_bounds__(256) void k_vred(const float* __restrict__ part, int P,
                                              float* __restrict__ part2) {
  int b = blockIdx.x, t = threadIdx.x;
  int chunk = (P + VRB - 1) / VRB;
  int lo = b * chunk, hi = min(P, lo + chunk);
  float s0 = 0.f, s1 = 0.f, s2 = 0.f, s3 = 0.f;
  int p = lo;
  for (; p + 3 < hi; p += 4) {
    s0 += part[(size_t)p * HID + t];
    s1 += part[(size_t)(p + 1) * HID + t];
    s2 += part[(size_t)(p + 2) * HID + t];
    s3 += part[(size_t)(p + 3) * HID + t];
  }
  for (; p < hi; p++) s0 += part[(size_t)p * HID + t];
  part2[(size_t)b * HID + t] = (s0 + s1) + (s2 + s3);
}

// ---------------- K11: v+gfeat reduce, embedding, MLP head, final transform ------------
__global__ __launch_bounds__(256) void k_head(const float* __restrict__ part2,
                                              const float* __restrict__ gpart, int NG,
                                              const float* __restrict__ W3,
                                              const float* __restrict__ b3,
                                              const float* __restrict__ Wp1,
                                              const float* __restrict__ bp1,
                                              const float* __restrict__ Wp2,
                                              const float* __restrict__ bp2,
                                              const float* __restrict__ Wp3,
                                              const float* __restrict__ bp3,
                                              float* __restrict__ out, int N) {
  __shared__ float vsh[HID];
  __shared__ float gred[256];
  __shared__ float gsh[8];
  __shared__ float emb2[256];
  __shared__ float emb[EMBD + 7];
  __shared__ float h64[64];
  __shared__ float h32[32];
  __shared__ float val[4];
  int t = threadIdx.x;
  {
    float s0 = 0.f, s1 = 0.f, s2 = 0.f, s3 = 0.f;
    #pragma unroll
    for (int p = 0; p < VRB; p += 4) {
      s0 += part2[(size_t)p * HID + t];
      s1 += part2[(size_t)(p + 1) * HID + t];
      s2 += part2[(size_t)(p + 2) * HID + t];
      s3 += part2[(size_t)(p + 3) * HID + t];
    }
    vsh[t] = (s0 + s1) + (s2 + s3);
  }
  {
    float g = 0.f;
    int j = t & 7;
    for (int p = t >> 3; p < NG; p += 32) g += gpart[(size_t)p * 8 + j];
    gred[t] = g;
  }
  __syncthreads();
  if (t < 8) {
    float tot = 0.f;
    for (int q = t; q < 256; q += 8) tot += gred[q];
    gsh[t] = tot;
  }
  // W3 matvec with all 256 threads: 2 threads per output dim
  {
    int dim = t & 127, ch = (t >> 7) * 128;
    float a0 = 0.f, a1 = 0.f, a2 = 0.f, a3 = 0.f;
    #pragma unroll 4
    for (int c = 0; c < 128; c += 4) {
      a0 = fmaf(vsh[ch + c + 0], W3[(size_t)(ch + c + 0) * EMBD + dim], a0);
      a1 = fmaf(vsh[ch + c + 1], W3[(size_t)(ch + c + 1) * EMBD + dim], a1);
      a2 = fmaf(vsh[ch + c + 2], W3[(size_t)(ch + c + 2) * EMBD + dim], a2);
      a3 = fmaf(vsh[ch + c + 3], W3[(size_t)(ch + c + 3) * EMBD + dim], a3);
    }
    emb2[t] = (a0 + a1) + (a2 + a3);
  }
  __syncthreads();
  if (t < EMBD) {
    emb[t] = (emb2[t] + emb2[t + 128]) / (float)N + b3[t];
  } else if (t == EMBD) {
    emb[EMBD + 0] = gsh[0];
    emb[EMBD + 1] = gsh[1];
    emb[EMBD + 2] = gsh[2];
    emb[EMBD + 3] = gsh[1] + gsh[2];
    float cnt = gsh[3];
    emb[EMBD + 4] = cnt > 0.f ? gsh[4] / fmaxf(cnt, 1.f) : 0.f;
    emb[EMBD + 5] = cnt > 0.f ? gsh[5] / fmaxf(cnt, 1.f) : 0.f;
    emb[EMBD + 6] = 100.0f / 500.0f;  // T_norm
  }
  __syncthreads();
  if (t < 64) {
    float a = bp1[t];
    for (int k = 0; k < EMBD + 7; k++) a = fmaf(emb[k], Wp1[k * 64 + t], a);
    h64[t] = fmaxf(a, 0.f);
  }
  __syncthreads();
  if (t < 32) {
    float a = bp2[t];
    for (int k = 0; k < 64; k++) a = fmaf(h64[k], Wp2[k * 32 + t], a);
    h32[t] = fmaxf(a, 0.f);
  }
  __syncthreads();
  if (t < 4) {
    float a = bp3[t];
    for (int k = 0; k < 32; k++) a = fmaf(h32[k], Wp3[k * 4 + t], a);
    val[t] = a > 20.f ? a : log1pf(expf(a));  // softplus
  }
  __syncthreads();
  if (t == 0) {
    const float Tn = 100.0f / 500.0f;
    const float scale = 1.0f - 0.7f * Tn;
    float am = 1.0f + val[0] * scale;
    float aM = 1.0f + (val[0] + val[1] + 1.0f) * scale;
    float bm = 1.0f + val[2] * scale * 0.3f;
    float bM = bm + (val[3] + 0.1f) * scale * 0.3f;
    out[0] = am; out[1] = aM; out[2] = bm; out[3] = bM;
  }
  if (t < EMBD + 7) out[4 + t] = emb[t];
}

static inline size_t al4(size_t a) { return (a + 3) & ~(size_t)3; }

extern "C" void kernel_launch(void* const* d_in, const int* in_sizes, int n_in,
                              void* d_out, int out_size, void* d_ws, size_t ws_size,
                              hipStream_t stream) {
  const float* x = (const float*)d_in[0];
  const int* ei = (const int*)d_in[1];
  const float* W1 = (const float*)d_in[2];
  const float* b1 = (const float*)d_in[3];
  const float* W2 = (const float*)d_in[4];
  const float* b2 = (const float*)d_in[5];
  const float* W3 = (const float*)d_in[6];
  const float* b3 = (const float*)d_in[7];
  const float* Wp1 = (const float*)d_in[8];
  const float* bp1 = (const float*)d_in[9];
  const float* Wp2 = (const float*)d_in[10];
  const float* bp2 = (const float*)d_in[11];
  const float* Wp3 = (const float*)d_in[12];
  const float* bp3 = (const float*)d_in[13];

  int N = in_sizes[0] / FIN;
  int E = in_sizes[1] / 2;
  int nb = (N + 255) / 256;
  int Npad = ((N + 255) / 256) * 256;   // multiple of 256
  int P = Npad / 256;                   // gemm2 blocks / partials
  int NB = (N + 63) / 64;               // buckets of 64 nodes
  int per = (E + NBLK - 1) / NBLK;      // edges per hist/place block
  size_t shbytes = (size_t)2 * NB * sizeof(int);

  float* ws = (float*)d_ws;
  size_t o_row  = 0;                                 // N+1 ints
  size_t o_inv  = al4(o_row + N + 1);                // N floats
  size_t o_w    = al4(o_inv + N);                    // N floats
  size_t o_part = al4(o_w + N);                      // P*256 floats
  size_t o_p2   = o_part + (size_t)P * HID;          // VRB*256 floats
  size_t o_gp   = o_p2 + (size_t)VRB * HID;          // NB*8 floats (gfeat partials)
  size_t o_xi   = al4(o_gp + (size_t)NB * 8);        // 4N (uint4/node)
  size_t o_w2t  = o_xi + (size_t)N * 4;              // 32768 (HID*HID bf16)
  size_t o_h2dD = o_w2t + (size_t)HID * HID / 2;     // NBLK*NB ints
  size_t o_h2dS = o_h2dD + (size_t)NBLK * NB;        // NBLK*NB ints
  size_t o_btot = o_h2dS + (size_t)NBLK * NB;        // 2*NB
  size_t o_bsD  = o_btot + (size_t)2 * NB;           // NB+1
  size_t o_bsS  = o_bsD + NB + 1;                    // NB+1
  size_t o_seD  = al4(o_bsS + NB + 1);               // E uints
  size_t o_seS  = o_seD + E;                         // E uints
  size_t o_csr  = o_seS + E;                         // E ints
  size_t o_g    = al4(o_csr + E);                    // 8N floats (generator vecs)
  size_t o_Z    = o_g + (size_t)N * 8;               // Npad x 256 bf16
  size_t total  = o_Z + (size_t)Npad * (HID / 2);
  if (ws_size < total * sizeof(float)) {
    hipMemsetAsync(d_out, 0x42, (size_t)out_size * sizeof(float), stream);
    return;
  }

  int* row = (int*)(ws + o_row);
  int* h2dD = (int*)(ws + o_h2dD);
  int* h2dS = (int*)(ws + o_h2dS);
  int* btot = (int*)(ws + o_btot);
  int* bsD = (int*)(ws + o_bsD);
  int* bsS = (int*)(ws + o_bsS);
  unsigned int* seD = (unsigned int*)(ws + o_seD);
  unsigned int* seS = (unsigned int*)(ws + o_seS);
  int* csr = (int*)(ws + o_csr);
  unsigned short* W2f = (unsigned short*)(ws + o_w2t);
  uint4* xi = (uint4*)(ws + o_xi);
  float4* g = (float4*)(ws + o_g);
  unsigned short* Zb = (unsigned short*)(ws + o_Z);

  k_hist<<<NBLK + HID, 256, shbytes, stream>>>(ei, W2, h2dD, h2dS, W2f, E, NB, per);
  k_bred<<<2 * NB, 256, 0, stream>>>(h2dD, h2dS, btot, NB);
  k_bscan<<<1, 256, 0, stream>>>(btot, bsD, bsS, row, E, NB, N);
  k_place<<<NBLK, 256, shbytes, stream>>>(ei, h2dD, h2dS, bsD, bsS, seD, seS, E, NB, per);
  k_csrd<<<NB, 256, 0, stream>>>(seD, bsD, x, csr, row, ws + o_inv, xi, ws + o_gp, NB, N);
  k_csrs<<<NB, 256, 0, stream>>>(seS, bsS, ws + o_inv, ws + o_w, NB, N);
  k_gvec<<<nb, 256, 0, stream>>>(xi, row, csr, ws + o_inv, g, ws + o_w, N);
  k_agg<<<Npad / 4, 256, 0, stream>>>(row, csr, ws + o_inv, g, W1, b1, Zb, N);
  k_gemm2<<<P, 256, 0, stream>>>(Zb, ws + o_w, W2f, b2, ws + o_part, N);
  k_vred<<<VRB, 256, 0, stream>>>(ws + o_part, P, ws + o_p2);
  k_head<<<1, 256, 0, stream>>>(ws + o_p2, ws + o_gp, NB, W3, b3, Wp1, bp1, Wp2, bp2,
                                Wp3, bp3, (float*)d_out, N);
}

// Round 14
// 264.528 us; speedup vs baseline: 1.1943x; 1.1943x over previous
//
#include <hip/hip_runtime.h>
#include <hip/hip_bf16.h>
#include <hip/hip_fp16.h>
#include <cstdint>
#include <cstddef>

#define HID 256
#define EMBD 128
#define FIN 5
#define NBLK 256   // histogram/placement blocks
#define VRB 32     // v-reduce blocks
#define BKT 512    // nodes per bucket
#define BSH 9      // log2(BKT)

typedef __attribute__((ext_vector_type(8))) short bf16x8;
typedef __attribute__((ext_vector_type(4))) float f32x4;
typedef __attribute__((ext_vector_type(2))) _Float16 half2v;

__device__ __forceinline__ unsigned short f2bf(float f) {
  unsigned int u = __float_as_uint(f);
  u += 0x7FFFu + ((u >> 16) & 1u);   // RNE
  return (unsigned short)(u >> 16);
}
__device__ __forceinline__ float bflo(unsigned int u) { return __uint_as_float(u << 16); }
__device__ __forceinline__ float bfhi(unsigned int u) { return __uint_as_float(u & 0xFFFF0000u); }
__device__ __forceinline__ unsigned int pack2bf(float a, float b) {
  return ((unsigned int)f2bf(b) << 16) | (unsigned int)f2bf(a);
}
// fp8 e5m2 = top byte of fp16, manual RNE
__device__ __forceinline__ unsigned char f2bf8(float f) {
  unsigned short u = __half_as_ushort(__float2half(f));
  unsigned short r = u + 0x7Fu + ((u >> 8) & 1u);
  return (unsigned char)(r >> 8);
}
__device__ __forceinline__ unsigned int pk4fp8(float a, float b, float c, float d) {
  return (unsigned int)f2bf8(a) | ((unsigned int)f2bf8(b) << 8) |
         ((unsigned int)f2bf8(c) << 16) | ((unsigned int)f2bf8(d) << 24);
}
// decode 4 e5m2 bytes of u as two f16 pairs and accumulate (2 bitops + 2 pk_add)
__device__ __forceinline__ void acc2h(half2v* h, unsigned int u) {
  unsigned int p0 = (u << 8) & 0xFF00FF00u;   // bytes 0,2 -> f16 (lo,hi)
  unsigned int p1 = u & 0xFF00FF00u;          // bytes 1,3 -> f16 (lo,hi)
  half2v v0, v1;
  __builtin_memcpy(&v0, &p0, 4);
  __builtin_memcpy(&v1, &p1, 4);
  h[0] += v0;
  h[1] += v1;
}
__device__ __forceinline__ void acc4h(half2v* h, uint4 r) {
  acc2h(h + 0, r.x); acc2h(h + 2, r.y);
  acc2h(h + 4, r.z); acc2h(h + 6, r.w);
}
__device__ __forceinline__ half2v h2shfl_xor(half2v v, int mask) {
  unsigned int b;
  __builtin_memcpy(&b, &v, 4);
  b = __shfl_xor(b, mask);
  half2v r;
  __builtin_memcpy(&r, &b, 4);
  return r;
}

// ---------------- K1: dual LDS histogram (dst & src buckets) + W2 -> fragment order ------
__global__ __launch_bounds__(256) void k_hist(const int* __restrict__ ei,
                                              const float* __restrict__ W2,
                                              int* __restrict__ h2dD,
                                              int* __restrict__ h2dS,
                                              unsigned short* __restrict__ W2f,
                                              int E, int NB, int per) {
  int b = blockIdx.x, t = threadIdx.x;
  if (b >= NBLK) {  // W2 pack blocks: b-NBLK = n (col), t = k
    int n = b - NBLK;
    size_t off = ((((size_t)(n >> 4) * 8 + (t >> 5)) * 64) +
                  (size_t)((t >> 3) & 3) * 16 + (n & 15)) * 8 + (t & 7);
    W2f[off] = f2bf(W2[(size_t)t * HID + n]);
    return;
  }
  extern __shared__ int hsh[];  // 2*NB ints
  int* hD = hsh;
  int* hS = hsh + NB;
  for (int j = t; j < 2 * NB; j += 256) hsh[j] = 0;
  __syncthreads();
  int lo = b * per, hi = min(E, lo + per);
  for (int e = lo + t; e < hi; e += 256) {
    int s = ei[e];
    int d = ei[(size_t)E + e];
    atomicAdd(&hD[d >> BSH], 1);
    atomicAdd(&hS[s >> BSH], 1);
  }
  __syncthreads();
  for (int j = t; j < NB; j += 256) {
    h2dD[(size_t)b * NB + j] = hD[j];
    h2dS[(size_t)b * NB + j] = hS[j];
  }
}

// ---------------- K2: per-bucket exclusive scan over blocks ----------------
__global__ __launch_bounds__(256) void k_bred(int* __restrict__ h2dD,
                                              int* __restrict__ h2dS,
                                              int* __restrict__ btot, int NB) {
  __shared__ int sh[NBLK];
  int bb = blockIdx.x, t = threadIdx.x;
  int* arr = (bb < NB) ? h2dD : h2dS;
  int b = (bb < NB) ? bb : bb - NB;
  int v = arr[(size_t)t * NB + b];
  sh[t] = v;
  __syncthreads();
  for (int off = 1; off < 256; off <<= 1) {
    int u = (t >= off) ? sh[t - off] : 0;
    __syncthreads();
    sh[t] += u;
    __syncthreads();
  }
  arr[(size_t)t * NB + b] = sh[t] - v;   // exclusive over blocks
  if (t == 255) btot[bb] = sh[255];
}

// ---------------- K3: scan bucket totals -> bucket starts ----------------
__global__ __launch_bounds__(256) void k_bscan(const int* __restrict__ btot,
                                               int* __restrict__ bsD,
                                               int* __restrict__ bsS,
                                               int* __restrict__ row,
                                               int E, int NB, int N) {
  __shared__ int sh[256];
  __shared__ int carrysh;
  int t = threadIdx.x;
  for (int which = 0; which < 2; which++) {
    const int* src = btot + (size_t)which * NB;
    int* dst = which ? bsS : bsD;
    if (t == 0) carrysh = 0;
    __syncthreads();
    int nch = (NB + 255) / 256;
    for (int c = 0; c < nch; c++) {
      int i = c * 256 + t;
      int v = (i < NB) ? src[i] : 0;
      sh[t] = v;
      __syncthreads();
      for (int off = 1; off < 256; off <<= 1) {
        int u = (t >= off) ? sh[t - off] : 0;
        __syncthreads();
        sh[t] += u;
        __syncthreads();
      }
      int carry = carrysh;
      if (i < NB) dst[i] = carry + sh[t] - v;
      __syncthreads();
      if (t == 255) carrysh = carry + sh[255];
      __syncthreads();
    }
    if (t == 0) dst[NB] = E;
    __syncthreads();
  }
  if (t == 0) row[N] = E;
}

// ---------------- K4: placement into bucket-sorted edge arrays (LDS counters only) --------
__global__ __launch_bounds__(256) void k_place(const int* __restrict__ ei,
                                               const int* __restrict__ h2dD,
                                               const int* __restrict__ h2dS,
                                               const int* __restrict__ bsD,
                                               const int* __restrict__ bsS,
                                               unsigned int* __restrict__ seD,
                                               unsigned int* __restrict__ seS,
                                               int E, int NB, int per) {
  extern __shared__ int osh[];  // 2*NB ints
  int* oD = osh;
  int* oS = osh + NB;
  int b = blockIdx.x, t = threadIdx.x;
  for (int j = t; j < NB; j += 256) {
    oD[j] = bsD[j] + h2dD[(size_t)b * NB + j];
    oS[j] = bsS[j] + h2dS[(size_t)b * NB + j];
  }
  __syncthreads();
  int lo = b * per, hi = min(E, lo + per);
  for (int e = lo + t; e < hi; e += 256) {
    int s = ei[e];
    int d = ei[(size_t)E + e];
    int pd = atomicAdd(&oD[d >> BSH], 1);
    seD[pd] = (unsigned int)s | ((unsigned int)(d & (BKT - 1)) << 20);
    int ps = atomicAdd(&oS[s >> BSH], 1);
    seS[ps] = (unsigned int)d | ((unsigned int)(s & (BKT - 1)) << 20);
  }
}

// ---------------- K5: per-bucket dst CSR finalize (512-node buckets): csr,row,inv,xi,gfeat
__global__ __launch_bounds__(256) void k_csrd(const unsigned int* __restrict__ seD,
                                              const int* __restrict__ bsD,
                                              const float* __restrict__ x,
                                              int* __restrict__ csr,
                                              int* __restrict__ row,
                                              float* __restrict__ inv,
                                              uint4* __restrict__ xi,
                                              float* __restrict__ gpart,
                                              int NB, int N) {
  __shared__ int cnt[BKT], ofs[BKT];
  __shared__ int sh[256];
  __shared__ float wsum[4][6];
  int b = blockIdx.x, t = threadIdx.x;
  cnt[t] = 0; cnt[t + 256] = 0;
  __syncthreads();
  int lo = bsD[b], hi = bsD[b + 1];
  for (int k = lo + t; k < hi; k += 256) atomicAdd(&cnt[seD[k] >> 20], 1);
  __syncthreads();
  int v0 = cnt[2 * t], v1 = cnt[2 * t + 1];
  int tot = v0 + v1;
  sh[t] = tot;
  __syncthreads();
  for (int off = 1; off < 256; off <<= 1) {
    int u = (t >= off) ? sh[t - off] : 0;
    __syncthreads();
    sh[t] += u;
    __syncthreads();
  }
  int exq = sh[t] - tot;          // exclusive prefix for this pair
  ofs[2 * t] = exq;
  ofs[2 * t + 1] = exq + v0;
  float s2 = 0.f, s3 = 0.f, s4 = 0.f, c0 = 0.f, sl = 0.f, sm = 0.f;
  #pragma unroll
  for (int j = 0; j < 2; j++) {
    int li = 2 * t + j;
    int node = b * BKT + li;
    if (node < N) {
      int c = j ? v1 : v0;
      row[node] = lo + (j ? exq + v0 : exq);
      float iv = rsqrtf((float)c + 1.0f);
      inv[node] = iv;
      float x0 = x[(size_t)node * 5 + 0];
      float x1 = x[(size_t)node * 5 + 1];
      float x2 = x[(size_t)node * 5 + 2];
      float x3 = x[(size_t)node * 5 + 3];
      float x4 = x[(size_t)node * 5 + 4];
      uint4 o;
      o.x = pack2bf(x0 * iv, x1 * iv);
      o.y = pack2bf(x2 * iv, x3 * iv);
      o.z = pack2bf(x4 * iv, 0.f);
      o.w = 0u;
      xi[node] = o;
      s2 += x2; s3 += x3; s4 += x4;
      if (x2 == 1.0f) { c0 += 1.f; sl += x0; sm += x1; }
    }
  }
  #pragma unroll
  for (int off = 32; off > 0; off >>= 1) {
    s2 += __shfl_down(s2, off);
    s3 += __shfl_down(s3, off);
    s4 += __shfl_down(s4, off);
    c0 += __shfl_down(c0, off);
    sl += __shfl_down(sl, off);
    sm += __shfl_down(sm, off);
  }
  if ((t & 63) == 0) {
    int wv = t >> 6;
    wsum[wv][0] = s2; wsum[wv][1] = s3; wsum[wv][2] = s4;
    wsum[wv][3] = c0; wsum[wv][4] = sl; wsum[wv][5] = sm;
  }
  __syncthreads();
  if (t < 8) {
    float g = 0.f;
    if (t < 6) g = wsum[0][t] + wsum[1][t] + wsum[2][t] + wsum[3][t];
    gpart[(size_t)b * 8 + t] = g;
  }
  for (int k = lo + t; k < hi; k += 256) {
    unsigned int v = seD[k];
    int p = atomicAdd(&ofs[v >> 20], 1);
    csr[lo + p] = (int)(v & 0xFFFFFu);
  }
}

// ---------------- K7: per-bucket src pass: w_raw[s] = sum inv[dst] (LDS only) ----------
__global__ __launch_bounds__(256) void k_csrs(const unsigned int* __restrict__ seS,
                                              const int* __restrict__ bsS,
                                              const float* __restrict__ inv,
                                              float* __restrict__ w, int NB, int N) {
  __shared__ float wa[BKT];
  int b = blockIdx.x, t = threadIdx.x;
  wa[t] = 0.f; wa[t + 256] = 0.f;
  __syncthreads();
  int lo = bsS[b], hi = bsS[b + 1];
  for (int k = lo + t; k < hi; k += 256) {
    unsigned int v = seS[k];
    atomicAdd(&wa[v >> 20], inv[v & 0xFFFFFu]);
  }
  __syncthreads();
  #pragma unroll
  for (int j = 0; j < 2; j++) {
    int node = b * BKT + t + j * 256;
    if (node < N) w[node] = wa[t + j * 256];
  }
}

// ---------------- K8: thread-per-node xi gather; H1' = inv*relu(U@W1+b1) -> fp8 --------
__global__ __launch_bounds__(256) void k_h1f(const uint4* __restrict__ xi,
                                             const int* __restrict__ row,
                                             const int* __restrict__ csr,
                                             const float* __restrict__ inv,
                                             const float* __restrict__ W1,
                                             const float* __restrict__ b1,
                                             unsigned char* __restrict__ H1q,
                                             float* __restrict__ w, int N) {
  __shared__ float W1sh[FIN][HID];
  __shared__ float b1sh[HID];
  int t = threadIdx.x;
  #pragma unroll
  for (int k = 0; k < FIN; k++) W1sh[k][t] = W1[k * HID + t];
  b1sh[t] = b1[t];
  int n = blockIdx.x * 256 + t;
  float a0 = 0.f, a1 = 0.f, a2 = 0.f, a3 = 0.f, a4 = 0.f;
  float invd = 0.f;
  if (n < N) {
    invd = inv[n];
    int start = row[n], end = row[n + 1];
    for (int e = start; e < end; e++) {
      uint4 vx = xi[csr[e]];
      a0 += bflo(vx.x); a1 += bfhi(vx.x);
      a2 += bflo(vx.y); a3 += bfhi(vx.y);
      a4 += bflo(vx.z);
    }
    uint4 vs = xi[n];
    a0 += bflo(vs.x); a1 += bfhi(vs.x);
    a2 += bflo(vs.y); a3 += bfhi(vs.y);
    a4 += bflo(vs.z);
    a0 *= invd; a1 *= invd; a2 *= invd; a3 *= invd; a4 *= invd;
    w[n] = invd * w[n] + invd * invd;  // finalize pooling weight
  }
  __syncthreads();
  if (n >= N) return;
  unsigned char* hrow = H1q + (size_t)n * HID;
  for (int c = 0; c < HID; c += 16) {
    float vv[16];
    #pragma unroll
    for (int j = 0; j < 16; j++) {
      float s = b1sh[c + j];
      s = fmaf(a0, W1sh[0][c + j], s);
      s = fmaf(a1, W1sh[1][c + j], s);
      s = fmaf(a2, W1sh[2][c + j], s);
      s = fmaf(a3, W1sh[3][c + j], s);
      s = fmaf(a4, W1sh[4][c + j], s);
      vv[j] = fmaxf(s, 0.f) * invd;   // H1' = inv * relu(...)
    }
    uint4 o;
    o.x = pk4fp8(vv[0], vv[1], vv[2], vv[3]);
    o.y = pk4fp8(vv[4], vv[5], vv[6], vv[7]);
    o.z = pk4fp8(vv[8], vv[9], vv[10], vv[11]);
    o.w = pk4fp8(vv[12], vv[13], vv[14], vv[15]);
    *(uint4*)(hrow + c) = o;
  }
}

// ---------------- K9: Z[d] = inv_d*(sum H1'[src] + H1'[d]) (fp8 row gather, f16 accum) --
// wave per node; 4 quarters of 16 lanes each own one edge (16B/lane); unroll x2.
__global__ __launch_bounds__(256) void k_agg(const int* __restrict__ row,
                                             const int* __restrict__ csr,
                                             const float* __restrict__ inv,
                                             const unsigned char* __restrict__ H1q,
                                             unsigned short* __restrict__ Zb, int N) {
  int wv = threadIdx.x >> 6;
  int l = threadIdx.x & 63;
  int q = l >> 4;       // quarter: which edge in flight
  int sl = l & 15;      // col group: cols sl*16 .. sl*16+15
  int d = blockIdx.x * 4 + wv;
  half2v hacc[8];
  #pragma unroll
  for (int j = 0; j < 8; j++) hacc[j] = (half2v){(_Float16)0.f, (_Float16)0.f};
  if (d >= N) {
    if (l < 32) {  // zero pad rows for k_gemm2
      uint4 z = {0u, 0u, 0u, 0u};
      *(uint4*)(Zb + (size_t)d * HID + (l & 15) * 16 + (l >> 4) * 8) = z;
    }
    return;
  }
  float invd = inv[d];
  int start = row[d], end = row[d + 1];
  int e = start + q;
  for (; e + 4 < end; e += 8) {   // 2 edges in flight per quarter
    int s0 = csr[e], s1 = csr[e + 4];
    uint4 r0 = *(const uint4*)(H1q + (size_t)s0 * HID + sl * 16);
    uint4 r1 = *(const uint4*)(H1q + (size_t)s1 * HID + sl * 16);
    acc4h(hacc, r0); acc4h(hacc, r1);
  }
  for (; e < end; e += 4) {
    uint4 r0 = *(const uint4*)(H1q + (size_t)csr[e] * HID + sl * 16);
    acc4h(hacc, r0);
  }
  if (q == 0) {  // self-loop term
    uint4 rs = *(const uint4*)(H1q + (size_t)d * HID + sl * 16);
    acc4h(hacc, rs);
  }
  #pragma unroll
  for (int j = 0; j < 8; j++) {
    hacc[j] += h2shfl_xor(hacc[j], 16);
    hacc[j] += h2shfl_xor(hacc[j], 32);
  }
  if (l < 32) {
    // unpack: chunk j covers cols 4j..4j+3; hacc[2j]=(c0,c2), hacc[2j+1]=(c1,c3)
    float vals[16];
    #pragma unroll
    for (int j = 0; j < 4; j++) {
      vals[4 * j + 0] = (float)hacc[2 * j][0];
      vals[4 * j + 2] = (float)hacc[2 * j][1];
      vals[4 * j + 1] = (float)hacc[2 * j + 1][0];
      vals[4 * j + 3] = (float)hacc[2 * j + 1][1];
    }
    int half = l >> 4;
    int base = half * 8;
    int col0 = (l & 15) * 16 + half * 8;
    uint4 o;
    o.x = pack2bf(vals[base + 0] * invd, vals[base + 1] * invd);
    o.y = pack2bf(vals[base + 2] * invd, vals[base + 3] * invd);
    o.z = pack2bf(vals[base + 4] * invd, vals[base + 5] * invd);
    o.w = pack2bf(vals[base + 6] * invd, vals[base + 7] * invd);
    *(uint4*)(Zb + (size_t)d * HID + col0) = o;
  }
}

// ---------------- K10: MFMA GEMM: H2 = relu(Z @ W2 + b2); part[blk] = H2^T w -----------
__global__ __launch_bounds__(256, 2) void k_gemm2(const unsigned short* __restrict__ Zb,
                                                  const float* __restrict__ w,
                                                  const unsigned short* __restrict__ W2f,
                                                  const float* __restrict__ b2,
                                                  float* __restrict__ part, int N) {
  __shared__ unsigned short Bsh[16384];  // 32 KB: 4 col-tiles x 8 kb x 64 lanes x 8
  __shared__ float vsh[4][HID];
  int t = threadIdx.x;
  int wv = t >> 6, l = t & 63;
  int lo = l & 15, hi = l >> 4;
  int row0 = blockIdx.x * 256 + wv * 64;

  bf16x8 a[4][8];
  #pragma unroll
  for (int rt = 0; rt < 4; rt++) {
    const unsigned short* zrow = Zb + (size_t)(row0 + rt * 16 + lo) * HID + hi * 8;
    #pragma unroll
    for (int kb = 0; kb < 8; kb++)
      a[rt][kb] = *reinterpret_cast<const bf16x8*>(zrow + kb * 32);
  }
  float w4[4][4];
  #pragma unroll
  for (int rt = 0; rt < 4; rt++)
    #pragma unroll
    for (int i = 0; i < 4; i++) {
      int gr = row0 + rt * 16 + hi * 4 + i;
      w4[rt][i] = (gr < N) ? w[gr] : 0.f;
    }

  for (int c = 0; c < 4; c++) {  // chunk of 4 col-tiles
    {
      const uint4* src = (const uint4*)(W2f + (size_t)c * 16384);
      uint4* dst = (uint4*)Bsh;
      #pragma unroll
      for (int i = 0; i < 8; i++) dst[t + i * 256] = src[t + i * 256];
    }
    __syncthreads();
    #pragma unroll
    for (int cp = 0; cp < 2; cp++) {
      int ct2 = cp * 2;
      f32x4 acc[2][4];
      #pragma unroll
      for (int u = 0; u < 2; u++)
        #pragma unroll
        for (int rt = 0; rt < 4; rt++) acc[u][rt] = (f32x4){0.f, 0.f, 0.f, 0.f};
      #pragma unroll
      for (int kb = 0; kb < 8; kb++) {
        bf16x8 b0 = *reinterpret_cast<const bf16x8*>(Bsh + ((ct2 * 8 + kb) * 64 + l) * 8);
        bf16x8 b1 = *reinterpret_cast<const bf16x8*>(Bsh + (((ct2 + 1) * 8 + kb) * 64 + l) * 8);
        #pragma unroll
        for (int rt = 0; rt < 4; rt++) {
          acc[0][rt] = __builtin_amdgcn_mfma_f32_16x16x32_bf16(a[rt][kb], b0, acc[0][rt], 0, 0, 0);
          acc[1][rt] = __builtin_amdgcn_mfma_f32_16x16x32_bf16(a[rt][kb], b1, acc[1][rt], 0, 0, 0);
        }
      }
      #pragma unroll
      for (int u = 0; u < 2; u++) {
        int col = (c * 4 + ct2 + u) * 16 + lo;
        float bc = b2[col];
        float p = 0.f;
        #pragma unroll
        for (int rt = 0; rt < 4; rt++)
          #pragma unroll
          for (int i = 0; i < 4; i++)
            p = fmaf(w4[rt][i], fmaxf(acc[u][rt][i] + bc, 0.f), p);
        p += __shfl_xor(p, 16);
        p += __shfl_xor(p, 32);
        if (hi == 0) vsh[wv][col] = p;
      }
    }
    __syncthreads();
  }
  float s = vsh[0][t] + vsh[1][t] + vsh[2][t] + vsh[3][t];
  part[(size_t)blockIdx.x * HID + t] = s;
}

// ---------------- K10b: parallel partial reduce part[P][256] -> part2[VRB][256] --------
__global__ __launch_bounds__(256) void k_vred(const float* __restrict__ part, int P,
                                              float* __restrict__ part2) {
  int b = blockIdx.x, t = threadIdx.x;
  int chunk = (P + VRB - 1) / VRB;
  int lo = b * chunk, hi = min(P, lo + chunk);
  float s0 = 0.f, s1 = 0.f, s2 = 0.f, s3 = 0.f;
  int p = lo;
  for (; p + 3 < hi; p += 4) {
    s0 += part[(size_t)p * HID + t];
    s1 += part[(size_t)(p + 1) * HID + t];
    s2 += part[(size_t)(p + 2) * HID + t];
    s3 += part[(size_t)(p + 3) * HID + t];
  }
  for (; p < hi; p++) s0 += part[(size_t)p * HID + t];
  part2[(size_t)b * HID + t] = (s0 + s1) + (s2 + s3);
}

// ---------------- K11: v+gfeat reduce, embedding, MLP head, final transform ------------
__global__ __launch_bounds__(256) void k_head(const float* __restrict__ part2,
                                              const float* __restrict__ gpart, int NG,
                                              const float* __restrict__ W3,
                                              const float* __restrict__ b3,
                                              const float* __restrict__ Wp1,
                                              const float* __restrict__ bp1,
                                              const float* __restrict__ Wp2,
                                              const float* __restrict__ bp2,
                                              const float* __restrict__ Wp3,
                                              const float* __restrict__ bp3,
                                              float* __restrict__ out, int N) {
  __shared__ float vsh[HID];
  __shared__ float gred[256];
  __shared__ float gsh[8];
  __shared__ float emb2[256];
  __shared__ float emb[EMBD + 7];
  __shared__ float h64[64];
  __shared__ float h32[32];
  __shared__ float val[4];
  int t = threadIdx.x;
  {
    float s0 = 0.f, s1 = 0.f, s2 = 0.f, s3 = 0.f;
    #pragma unroll
    for (int p = 0; p < VRB; p += 4) {
      s0 += part2[(size_t)p * HID + t];
      s1 += part2[(size_t)(p + 1) * HID + t];
      s2 += part2[(size_t)(p + 2) * HID + t];
      s3 += part2[(size_t)(p + 3) * HID + t];
    }
    vsh[t] = (s0 + s1) + (s2 + s3);
  }
  {
    float g = 0.f;
    int j = t & 7;
    for (int p = t >> 3; p < NG; p += 32) g += gpart[(size_t)p * 8 + j];
    gred[t] = g;
  }
  __syncthreads();
  if (t < 8) {
    float tot = 0.f;
    for (int q = t; q < 256; q += 8) tot += gred[q];
    gsh[t] = tot;
  }
  // W3 matvec with all 256 threads: 2 threads per output dim
  {
    int dim = t & 127, ch = (t >> 7) * 128;
    float a0 = 0.f, a1 = 0.f, a2 = 0.f, a3 = 0.f;
    #pragma unroll 4
    for (int c = 0; c < 128; c += 4) {
      a0 = fmaf(vsh[ch + c + 0], W3[(size_t)(ch + c + 0) * EMBD + dim], a0);
      a1 = fmaf(vsh[ch + c + 1], W3[(size_t)(ch + c + 1) * EMBD + dim], a1);
      a2 = fmaf(vsh[ch + c + 2], W3[(size_t)(ch + c + 2) * EMBD + dim], a2);
      a3 = fmaf(vsh[ch + c + 3], W3[(size_t)(ch + c + 3) * EMBD + dim], a3);
    }
    emb2[t] = (a0 + a1) + (a2 + a3);
  }
  __syncthreads();
  if (t < EMBD) {
    emb[t] = (emb2[t] + emb2[t + 128]) / (float)N + b3[t];
  } else if (t == EMBD) {
    emb[EMBD + 0] = gsh[0];
    emb[EMBD + 1] = gsh[1];
    emb[EMBD + 2] = gsh[2];
    emb[EMBD + 3] = gsh[1] + gsh[2];
    float cnt = gsh[3];
    emb[EMBD + 4] = cnt > 0.f ? gsh[4] / fmaxf(cnt, 1.f) : 0.f;
    emb[EMBD + 5] = cnt > 0.f ? gsh[5] / fmaxf(cnt, 1.f) : 0.f;
    emb[EMBD + 6] = 100.0f / 500.0f;  // T_norm
  }
  __syncthreads();
  if (t < 64) {
    float a = bp1[t];
    for (int k = 0; k < EMBD + 7; k++) a = fmaf(emb[k], Wp1[k * 64 + t], a);
    h64[t] = fmaxf(a, 0.f);
  }
  __syncthreads();
  if (t < 32) {
    float a = bp2[t];
    for (int k = 0; k < 64; k++) a = fmaf(h64[k], Wp2[k * 32 + t], a);
    h32[t] = fmaxf(a, 0.f);
  }
  __syncthreads();
  if (t < 4) {
    float a = bp3[t];
    for (int k = 0; k < 32; k++) a = fmaf(h32[k], Wp3[k * 4 + t], a);
    val[t] = a > 20.f ? a : log1pf(expf(a));  // softplus
  }
  __syncthreads();
  if (t == 0) {
    const float Tn = 100.0f / 500.0f;
    const float scale = 1.0f - 0.7f * Tn;
    float am = 1.0f + val[0] * scale;
    float aM = 1.0f + (val[0] + val[1] + 1.0f) * scale;
    float bm = 1.0f + val[2] * scale * 0.3f;
    float bM = bm + (val[3] + 0.1f) * scale * 0.3f;
    out[0] = am; out[1] = aM; out[2] = bm; out[3] = bM;
  }
  if (t < EMBD + 7) out[4 + t] = emb[t];
}

static inline size_t al4(size_t a) { return (a + 3) & ~(size_t)3; }

extern "C" void kernel_launch(void* const* d_in, const int* in_sizes, int n_in,
                              void* d_out, int out_size, void* d_ws, size_t ws_size,
                              hipStream_t stream) {
  const float* x = (const float*)d_in[0];
  const int* ei = (const int*)d_in[1];
  const float* W1 = (const float*)d_in[2];
  const float* b1 = (const float*)d_in[3];
  const float* W2 = (const float*)d_in[4];
  const float* b2 = (const float*)d_in[5];
  const float* W3 = (const float*)d_in[6];
  const float* b3 = (const float*)d_in[7];
  const float* Wp1 = (const float*)d_in[8];
  const float* bp1 = (const float*)d_in[9];
  const float* Wp2 = (const float*)d_in[10];
  const float* bp2 = (const float*)d_in[11];
  const float* Wp3 = (const float*)d_in[12];
  const float* bp3 = (const float*)d_in[13];

  int N = in_sizes[0] / FIN;
  int E = in_sizes[1] / 2;
  int nb = (N + 255) / 256;
  int Npad = ((N + 255) / 256) * 256;   // multiple of 256
  int P = Npad / 256;                   // gemm2 blocks / partials
  int NB = (N + BKT - 1) / BKT;         // buckets of 512 nodes
  int per = (E + NBLK - 1) / NBLK;      // edges per hist/place block
  size_t shbytes = (size_t)2 * NB * sizeof(int);

  float* ws = (float*)d_ws;
  size_t o_row  = 0;                                 // N+1 ints
  size_t o_inv  = al4(o_row + N + 1);                // N floats
  size_t o_w    = al4(o_inv + N);                    // N floats
  size_t o_part = al4(o_w + N);                      // P*256 floats
  size_t o_p2   = o_part + (size_t)P * HID;          // VRB*256 floats
  size_t o_gp   = o_p2 + (size_t)VRB * HID;          // NB*8 floats (gfeat partials)
  size_t o_xi   = al4(o_gp + (size_t)NB * 8);        // 4N (uint4/node)
  size_t o_w2t  = o_xi + (size_t)N * 4;              // 32768 (HID*HID bf16)
  size_t o_h2dD = o_w2t + (size_t)HID * HID / 2;     // NBLK*NB ints
  size_t o_h2dS = o_h2dD + (size_t)NBLK * NB;        // NBLK*NB ints
  size_t o_btot = o_h2dS + (size_t)NBLK * NB;        // 2*NB
  size_t o_bsD  = o_btot + (size_t)2 * NB;           // NB+1
  size_t o_bsS  = o_bsD + NB + 1;                    // NB+1
  size_t o_seD  = al4(o_bsS + NB + 1);               // E uints
  size_t o_seS  = o_seD + E;                         // E uints
  size_t o_csr  = o_seS + E;                         // E ints
  size_t o_H1q  = al4(o_csr + E);                    // N x 256 B (fp8 rows)
  size_t o_Z    = o_H1q + (size_t)N * (HID / 4);     // Npad x 256 bf16
  size_t total  = o_Z + (size_t)Npad * (HID / 2);
  if (ws_size < total * sizeof(float)) {
    hipMemsetAsync(d_out, 0x42, (size_t)out_size * sizeof(float), stream);
    return;
  }

  int* row = (int*)(ws + o_row);
  int* h2dD = (int*)(ws + o_h2dD);
  int* h2dS = (int*)(ws + o_h2dS);
  int* btot = (int*)(ws + o_btot);
  int* bsD = (int*)(ws + o_bsD);
  int* bsS = (int*)(ws + o_bsS);
  unsigned int* seD = (unsigned int*)(ws + o_seD);
  unsigned int* seS = (unsigned int*)(ws + o_seS);
  int* csr = (int*)(ws + o_csr);
  unsigned short* W2f = (unsigned short*)(ws + o_w2t);
  uint4* xi = (uint4*)(ws + o_xi);
  unsigned char* H1q = (unsigned char*)(ws + o_H1q);
  unsigned short* Zb = (unsigned short*)(ws + o_Z);

  k_hist<<<NBLK + HID, 256, shbytes, stream>>>(ei, W2, h2dD, h2dS, W2f, E, NB, per);
  k_bred<<<2 * NB, 256, 0, stream>>>(h2dD, h2dS, btot, NB);
  k_bscan<<<1, 256, 0, stream>>>(btot, bsD, bsS, row, E, NB, N);
  k_place<<<NBLK, 256, shbytes, stream>>>(ei, h2dD, h2dS, bsD, bsS, seD, seS, E, NB, per);
  k_csrd<<<NB, 256, 0, stream>>>(seD, bsD, x, csr, row, ws + o_inv, xi, ws + o_gp, NB, N);
  k_csrs<<<NB, 256, 0, stream>>>(seS, bsS, ws + o_inv, ws + o_w, NB, N);
  k_h1f<<<nb, 256, 0, stream>>>(xi, row, csr, ws + o_inv, W1, b1, H1q, ws + o_w, N);
  k_agg<<<Npad / 4, 256, 0, stream>>>(row, csr, ws + o_inv, H1q, Zb, N);
  k_gemm2<<<P, 256, 0, stream>>>(Zb, ws + o_w, W2f, b2, ws + o_part, N);
  k_vred<<<VRB, 256, 0, stream>>>(ws + o_part, P, ws + o_p2);
  k_head<<<1, 256, 0, stream>>>(ws + o_p2, ws + o_gp, NB, W3, b3, Wp1, bp1, Wp2, bp2,
                                Wp3, bp3, (float*)d_out, N);
}

// Round 15
// 260.170 us; speedup vs baseline: 1.2143x; 1.0168x over previous
//
#include <hip/hip_runtime.h>
#include <hip/hip_bf16.h>
#include <hip/hip_fp16.h>
#include <cstdint>
#include <cstddef>

#define HID 256
#define EMBD 128
#define FIN 5
#define NBLK 256   // histogram/placement blocks
#define VRB 32     // v-reduce blocks
#define BKT 512    // nodes per bucket
#define BSH 9      // log2(BKT)

typedef __attribute__((ext_vector_type(4))) float f32x4;
typedef __attribute__((ext_vector_type(2))) _Float16 half2v;

__device__ __forceinline__ unsigned short f2bf(float f) {
  unsigned int u = __float_as_uint(f);
  u += 0x7FFFu + ((u >> 16) & 1u);   // RNE
  return (unsigned short)(u >> 16);
}
__device__ __forceinline__ float bflo(unsigned int u) { return __uint_as_float(u << 16); }
__device__ __forceinline__ float bfhi(unsigned int u) { return __uint_as_float(u & 0xFFFF0000u); }
__device__ __forceinline__ unsigned int pack2bf(float a, float b) {
  return ((unsigned int)f2bf(b) << 16) | (unsigned int)f2bf(a);
}
// fp8 e5m2 = top byte of fp16, manual RNE
__device__ __forceinline__ unsigned char f2bf8(float f) {
  unsigned short u = __half_as_ushort(__float2half(f));
  unsigned short r = u + 0x7Fu + ((u >> 8) & 1u);
  return (unsigned char)(r >> 8);
}
__device__ __forceinline__ unsigned int pk4fp8(float a, float b, float c, float d) {
  return (unsigned int)f2bf8(a) | ((unsigned int)f2bf8(b) << 8) |
         ((unsigned int)f2bf8(c) << 16) | ((unsigned int)f2bf8(d) << 24);
}
// decode 4 e5m2 bytes of u as two f16 pairs and accumulate (2 bitops + 2 pk_add)
__device__ __forceinline__ void acc2h(half2v* h, unsigned int u) {
  unsigned int p0 = (u << 8) & 0xFF00FF00u;   // bytes 0,2 -> f16 (lo,hi)
  unsigned int p1 = u & 0xFF00FF00u;          // bytes 1,3 -> f16 (lo,hi)
  half2v v0, v1;
  __builtin_memcpy(&v0, &p0, 4);
  __builtin_memcpy(&v1, &p1, 4);
  h[0] += v0;
  h[1] += v1;
}
__device__ __forceinline__ void acc4h(half2v* h, uint4 r) {
  acc2h(h + 0, r.x); acc2h(h + 2, r.y);
  acc2h(h + 4, r.z); acc2h(h + 6, r.w);
}
__device__ __forceinline__ half2v h2shfl_xor(half2v v, int mask) {
  unsigned int b;
  __builtin_memcpy(&b, &v, 4);
  b = __shfl_xor(b, mask);
  half2v r;
  __builtin_memcpy(&r, &b, 4);
  return r;
}

// ---------------- K1: dual LDS histogram (dst & src buckets) + W2 -> bf8 fragment order --
// W2f8: B-frag for col-tile ct, k-block kb, lane (hi*16+lo), elem j (8 bytes/lane):
//   W2f8[(((ct*8+kb)*64 + hi*16+lo))*8 + j] = bf8(W2[kb*32+hi*8+j][ct*16+lo])
__global__ __launch_bounds__(256) void k_hist(const int* __restrict__ ei,
                                              const float* __restrict__ W2,
                                              int* __restrict__ h2dD,
                                              int* __restrict__ h2dS,
                                              unsigned char* __restrict__ W2f8,
                                              int E, int NB, int per) {
  int b = blockIdx.x, t = threadIdx.x;
  if (b >= NBLK) {  // W2 pack blocks: b-NBLK = n (col), t = k
    int n = b - NBLK;
    size_t off = ((((size_t)(n >> 4) * 8 + (t >> 5)) * 64) +
                  (size_t)((t >> 3) & 3) * 16 + (n & 15)) * 8 + (t & 7);
    W2f8[off] = f2bf8(W2[(size_t)t * HID + n]);
    return;
  }
  extern __shared__ int hsh[];  // 2*NB ints
  int* hD = hsh;
  int* hS = hsh + NB;
  for (int j = t; j < 2 * NB; j += 256) hsh[j] = 0;
  __syncthreads();
  int lo = b * per, hi = min(E, lo + per);
  for (int e = lo + t; e < hi; e += 256) {
    int s = ei[e];
    int d = ei[(size_t)E + e];
    atomicAdd(&hD[d >> BSH], 1);
    atomicAdd(&hS[s >> BSH], 1);
  }
  __syncthreads();
  for (int j = t; j < NB; j += 256) {
    h2dD[(size_t)b * NB + j] = hD[j];
    h2dS[(size_t)b * NB + j] = hS[j];
  }
}

// ---------------- K2: per-bucket exclusive scan over blocks ----------------
__global__ __launch_bounds__(256) void k_bred(int* __restrict__ h2dD,
                                              int* __restrict__ h2dS,
                                              int* __restrict__ btot, int NB) {
  __shared__ int sh[NBLK];
  int bb = blockIdx.x, t = threadIdx.x;
  int* arr = (bb < NB) ? h2dD : h2dS;
  int b = (bb < NB) ? bb : bb - NB;
  int v = arr[(size_t)t * NB + b];
  sh[t] = v;
  __syncthreads();
  for (int off = 1; off < 256; off <<= 1) {
    int u = (t >= off) ? sh[t - off] : 0;
    __syncthreads();
    sh[t] += u;
    __syncthreads();
  }
  arr[(size_t)t * NB + b] = sh[t] - v;   // exclusive over blocks
  if (t == 255) btot[bb] = sh[255];
}

// ---------------- K3: scan bucket totals -> bucket starts ----------------
__global__ __launch_bounds__(256) void k_bscan(const int* __restrict__ btot,
                                               int* __restrict__ bsD,
                                               int* __restrict__ bsS,
                                               int* __restrict__ row,
                                               int E, int NB, int N) {
  __shared__ int sh[256];
  __shared__ int carrysh;
  int t = threadIdx.x;
  for (int which = 0; which < 2; which++) {
    const int* src = btot + (size_t)which * NB;
    int* dst = which ? bsS : bsD;
    if (t == 0) carrysh = 0;
    __syncthreads();
    int nch = (NB + 255) / 256;
    for (int c = 0; c < nch; c++) {
      int i = c * 256 + t;
      int v = (i < NB) ? src[i] : 0;
      sh[t] = v;
      __syncthreads();
      for (int off = 1; off < 256; off <<= 1) {
        int u = (t >= off) ? sh[t - off] : 0;
        __syncthreads();
        sh[t] += u;
        __syncthreads();
      }
      int carry = carrysh;
      if (i < NB) dst[i] = carry + sh[t] - v;
      __syncthreads();
      if (t == 255) carrysh = carry + sh[255];
      __syncthreads();
    }
    if (t == 0) dst[NB] = E;
    __syncthreads();
  }
  if (t == 0) row[N] = E;
}

// ---------------- K4: placement into bucket-sorted edge arrays (LDS counters only) --------
__global__ __launch_bounds__(256) void k_place(const int* __restrict__ ei,
                                               const int* __restrict__ h2dD,
                                               const int* __restrict__ h2dS,
                                               const int* __restrict__ bsD,
                                               const int* __restrict__ bsS,
                                               unsigned int* __restrict__ seD,
                                               unsigned int* __restrict__ seS,
                                               int E, int NB, int per) {
  extern __shared__ int osh[];  // 2*NB ints
  int* oD = osh;
  int* oS = osh + NB;
  int b = blockIdx.x, t = threadIdx.x;
  for (int j = t; j < NB; j += 256) {
    oD[j] = bsD[j] + h2dD[(size_t)b * NB + j];
    oS[j] = bsS[j] + h2dS[(size_t)b * NB + j];
  }
  __syncthreads();
  int lo = b * per, hi = min(E, lo + per);
  for (int e = lo + t; e < hi; e += 256) {
    int s = ei[e];
    int d = ei[(size_t)E + e];
    int pd = atomicAdd(&oD[d >> BSH], 1);
    seD[pd] = (unsigned int)s | ((unsigned int)(d & (BKT - 1)) << 20);
    int ps = atomicAdd(&oS[s >> BSH], 1);
    seS[ps] = (unsigned int)d | ((unsigned int)(s & (BKT - 1)) << 20);
  }
}

// ---------------- K5: per-bucket dst CSR finalize (512-node buckets): csr,row,inv,xi,gfeat
__global__ __launch_bounds__(256) void k_csrd(const unsigned int* __restrict__ seD,
                                              const int* __restrict__ bsD,
                                              const float* __restrict__ x,
                                              int* __restrict__ csr,
                                              int* __restrict__ row,
                                              float* __restrict__ inv,
                                              uint4* __restrict__ xi,
                                              float* __restrict__ gpart,
                                              int NB, int N) {
  __shared__ int cnt[BKT], ofs[BKT];
  __shared__ int sh[256];
  __shared__ float wsum[4][6];
  int b = blockIdx.x, t = threadIdx.x;
  cnt[t] = 0; cnt[t + 256] = 0;
  __syncthreads();
  int lo = bsD[b], hi = bsD[b + 1];
  for (int k = lo + t; k < hi; k += 256) atomicAdd(&cnt[seD[k] >> 20], 1);
  __syncthreads();
  int v0 = cnt[2 * t], v1 = cnt[2 * t + 1];
  int tot = v0 + v1;
  sh[t] = tot;
  __syncthreads();
  for (int off = 1; off < 256; off <<= 1) {
    int u = (t >= off) ? sh[t - off] : 0;
    __syncthreads();
    sh[t] += u;
    __syncthreads();
  }
  int exq = sh[t] - tot;          // exclusive prefix for this pair
  ofs[2 * t] = exq;
  ofs[2 * t + 1] = exq + v0;
  float s2 = 0.f, s3 = 0.f, s4 = 0.f, c0 = 0.f, sl = 0.f, sm = 0.f;
  #pragma unroll
  for (int j = 0; j < 2; j++) {
    int li = 2 * t + j;
    int node = b * BKT + li;
    if (node < N) {
      int c = j ? v1 : v0;
      row[node] = lo + (j ? exq + v0 : exq);
      float iv = rsqrtf((float)c + 1.0f);
      inv[node] = iv;
      float x0 = x[(size_t)node * 5 + 0];
      float x1 = x[(size_t)node * 5 + 1];
      float x2 = x[(size_t)node * 5 + 2];
      float x3 = x[(size_t)node * 5 + 3];
      float x4 = x[(size_t)node * 5 + 4];
      uint4 o;
      o.x = pack2bf(x0 * iv, x1 * iv);
      o.y = pack2bf(x2 * iv, x3 * iv);
      o.z = pack2bf(x4 * iv, 0.f);
      o.w = 0u;
      xi[node] = o;
      s2 += x2; s3 += x3; s4 += x4;
      if (x2 == 1.0f) { c0 += 1.f; sl += x0; sm += x1; }
    }
  }
  #pragma unroll
  for (int off = 32; off > 0; off >>= 1) {
    s2 += __shfl_down(s2, off);
    s3 += __shfl_down(s3, off);
    s4 += __shfl_down(s4, off);
    c0 += __shfl_down(c0, off);
    sl += __shfl_down(sl, off);
    sm += __shfl_down(sm, off);
  }
  if ((t & 63) == 0) {
    int wv = t >> 6;
    wsum[wv][0] = s2; wsum[wv][1] = s3; wsum[wv][2] = s4;
    wsum[wv][3] = c0; wsum[wv][4] = sl; wsum[wv][5] = sm;
  }
  __syncthreads();
  if (t < 8) {
    float g = 0.f;
    if (t < 6) g = wsum[0][t] + wsum[1][t] + wsum[2][t] + wsum[3][t];
    gpart[(size_t)b * 8 + t] = g;
  }
  for (int k = lo + t; k < hi; k += 256) {
    unsigned int v = seD[k];
    int p = atomicAdd(&ofs[v >> 20], 1);
    csr[lo + p] = (int)(v & 0xFFFFFu);
  }
}

// ---------------- K7: per-bucket src pass: w_raw[s] = sum inv[dst] (LDS only) ----------
__global__ __launch_bounds__(256) void k_csrs(const unsigned int* __restrict__ seS,
                                              const int* __restrict__ bsS,
                                              const float* __restrict__ inv,
                                              float* __restrict__ w, int NB, int N) {
  __shared__ float wa[BKT];
  int b = blockIdx.x, t = threadIdx.x;
  wa[t] = 0.f; wa[t + 256] = 0.f;
  __syncthreads();
  int lo = bsS[b], hi = bsS[b + 1];
  for (int k = lo + t; k < hi; k += 256) {
    unsigned int v = seS[k];
    atomicAdd(&wa[v >> 20], inv[v & 0xFFFFFu]);
  }
  __syncthreads();
  #pragma unroll
  for (int j = 0; j < 2; j++) {
    int node = b * BKT + t + j * 256;
    if (node < N) w[node] = wa[t + j * 256];
  }
}

// ---------------- K8: thread-per-node xi gather; H1' = inv*relu(U@W1+b1) -> fp8 --------
__global__ __launch_bounds__(256) void k_h1f(const uint4* __restrict__ xi,
                                             const int* __restrict__ row,
                                             const int* __restrict__ csr,
                                             const float* __restrict__ inv,
                                             const float* __restrict__ W1,
                                             const float* __restrict__ b1,
                                             unsigned char* __restrict__ H1q,
                                             float* __restrict__ w, int N) {
  __shared__ float W1sh[FIN][HID];
  __shared__ float b1sh[HID];
  int t = threadIdx.x;
  #pragma unroll
  for (int k = 0; k < FIN; k++) W1sh[k][t] = W1[k * HID + t];
  b1sh[t] = b1[t];
  int n = blockIdx.x * 256 + t;
  float a0 = 0.f, a1 = 0.f, a2 = 0.f, a3 = 0.f, a4 = 0.f;
  float invd = 0.f;
  if (n < N) {
    invd = inv[n];
    int start = row[n], end = row[n + 1];
    for (int e = start; e < end; e++) {
      uint4 vx = xi[csr[e]];
      a0 += bflo(vx.x); a1 += bfhi(vx.x);
      a2 += bflo(vx.y); a3 += bfhi(vx.y);
      a4 += bflo(vx.z);
    }
    uint4 vs = xi[n];
    a0 += bflo(vs.x); a1 += bfhi(vs.x);
    a2 += bflo(vs.y); a3 += bfhi(vs.y);
    a4 += bflo(vs.z);
    a0 *= invd; a1 *= invd; a2 *= invd; a3 *= invd; a4 *= invd;
    w[n] = invd * w[n] + invd * invd;  // finalize pooling weight
  }
  __syncthreads();
  if (n >= N) return;
  unsigned char* hrow = H1q + (size_t)n * HID;
  for (int c = 0; c < HID; c += 16) {
    float vv[16];
    #pragma unroll
    for (int j = 0; j < 16; j++) {
      float s = b1sh[c + j];
      s = fmaf(a0, W1sh[0][c + j], s);
      s = fmaf(a1, W1sh[1][c + j], s);
      s = fmaf(a2, W1sh[2][c + j], s);
      s = fmaf(a3, W1sh[3][c + j], s);
      s = fmaf(a4, W1sh[4][c + j], s);
      vv[j] = fmaxf(s, 0.f) * invd;   // H1' = inv * relu(...)
    }
    uint4 o;
    o.x = pk4fp8(vv[0], vv[1], vv[2], vv[3]);
    o.y = pk4fp8(vv[4], vv[5], vv[6], vv[7]);
    o.z = pk4fp8(vv[8], vv[9], vv[10], vv[11]);
    o.w = pk4fp8(vv[12], vv[13], vv[14], vv[15]);
    *(uint4*)(hrow + c) = o;
  }
}

// ---------------- K9: Z[d] = inv_d*(sum H1'[src] + H1'[d]) (fp8 gather -> bf8 out) ------
// wave per node; 4 quarters of 16 lanes each own one edge (16B/lane); unroll x2.
__global__ __launch_bounds__(256) void k_agg(const int* __restrict__ row,
                                             const int* __restrict__ csr,
                                             const float* __restrict__ inv,
                                             const unsigned char* __restrict__ H1q,
                                             unsigned char* __restrict__ Zq, int N) {
  int wv = threadIdx.x >> 6;
  int l = threadIdx.x & 63;
  int q = l >> 4;       // quarter: which edge in flight
  int sl = l & 15;      // col group: cols sl*16 .. sl*16+15
  int d = blockIdx.x * 4 + wv;
  half2v hacc[8];
  #pragma unroll
  for (int j = 0; j < 8; j++) hacc[j] = (half2v){(_Float16)0.f, (_Float16)0.f};
  if (d >= N) {
    if (l < 32) {  // zero pad rows for k_gemm2
      uint2 z = {0u, 0u};
      *(uint2*)(Zq + (size_t)d * HID + (l & 15) * 16 + (l >> 4) * 8) = z;
    }
    return;
  }
  float invd = inv[d];
  int start = row[d], end = row[d + 1];
  int e = start + q;
  for (; e + 4 < end; e += 8) {   // 2 edges in flight per quarter
    int s0 = csr[e], s1 = csr[e + 4];
    uint4 r0 = *(const uint4*)(H1q + (size_t)s0 * HID + sl * 16);
    uint4 r1 = *(const uint4*)(H1q + (size_t)s1 * HID + sl * 16);
    acc4h(hacc, r0); acc4h(hacc, r1);
  }
  for (; e < end; e += 4) {
    uint4 r0 = *(const uint4*)(H1q + (size_t)csr[e] * HID + sl * 16);
    acc4h(hacc, r0);
  }
  if (q == 0) {  // self-loop term
    uint4 rs = *(const uint4*)(H1q + (size_t)d * HID + sl * 16);
    acc4h(hacc, rs);
  }
  #pragma unroll
  for (int j = 0; j < 8; j++) {
    hacc[j] += h2shfl_xor(hacc[j], 16);
    hacc[j] += h2shfl_xor(hacc[j], 32);
  }
  if (l < 32) {
    // unpack: chunk j covers cols 4j..4j+3; hacc[2j]=(c0,c2), hacc[2j+1]=(c1,c3)
    float vals[16];
    #pragma unroll
    for (int j = 0; j < 4; j++) {
      vals[4 * j + 0] = (float)hacc[2 * j][0];
      vals[4 * j + 2] = (float)hacc[2 * j][1];
      vals[4 * j + 1] = (float)hacc[2 * j + 1][0];
      vals[4 * j + 3] = (float)hacc[2 * j + 1][1];
    }
    int half = l >> 4;
    int base = half * 8;
    int col0 = (l & 15) * 16 + half * 8;
    uint2 o;
    o.x = pk4fp8(vals[base + 0] * invd, vals[base + 1] * invd,
                 vals[base + 2] * invd, vals[base + 3] * invd);
    o.y = pk4fp8(vals[base + 4] * invd, vals[base + 5] * invd,
                 vals[base + 6] * invd, vals[base + 7] * invd);
    *(uint2*)(Zq + (size_t)d * HID + col0) = o;
  }
}

// ---------------- K10: bf8 MFMA GEMM: H2 = relu(Z @ W2 + b2); part[blk] = H2^T w --------
__global__ __launch_bounds__(256, 2) void k_gemm2(const unsigned char* __restrict__ Zq,
                                                  const float* __restrict__ w,
                                                  const unsigned char* __restrict__ W2f8,
                                                  const float* __restrict__ b2,
                                                  float* __restrict__ part, int N) {
  __shared__ long Bshl[2048];  // 16 KB: 4 col-tiles x 8 kb x 64 lanes x 8 bytes
  __shared__ float vsh[4][HID];
  int t = threadIdx.x;
  int wv = t >> 6, l = t & 63;
  int lo = l & 15, hi = l >> 4;
  int row0 = blockIdx.x * 256 + wv * 64;

  // A frags: row = row0+rt*16+lo, 8 bf8 at k = kb*32 + hi*8 + j
  long a[4][8];
  #pragma unroll
  for (int rt = 0; rt < 4; rt++) {
    const unsigned char* zrow = Zq + (size_t)(row0 + rt * 16 + lo) * HID + hi * 8;
    #pragma unroll
    for (int kb = 0; kb < 8; kb++)
      a[rt][kb] = *reinterpret_cast<const long*>(zrow + kb * 32);
  }
  float w4[4][4];
  #pragma unroll
  for (int rt = 0; rt < 4; rt++)
    #pragma unroll
    for (int i = 0; i < 4; i++) {
      int gr = row0 + rt * 16 + hi * 4 + i;
      w4[rt][i] = (gr < N) ? w[gr] : 0.f;
    }

  for (int c = 0; c < 4; c++) {  // chunk of 4 col-tiles (16 KB of W2f8)
    {
      const uint4* src = (const uint4*)(W2f8 + (size_t)c * 16384);
      uint4* dst = (uint4*)Bshl;
      #pragma unroll
      for (int i = 0; i < 4; i++) dst[t + i * 256] = src[t + i * 256];
    }
    __syncthreads();
    #pragma unroll
    for (int cp = 0; cp < 2; cp++) {
      int ct2 = cp * 2;
      f32x4 acc[2][4];
      #pragma unroll
      for (int u = 0; u < 2; u++)
        #pragma unroll
        for (int rt = 0; rt < 4; rt++) acc[u][rt] = (f32x4){0.f, 0.f, 0.f, 0.f};
      #pragma unroll
      for (int kb = 0; kb < 8; kb++) {
        long b0 = Bshl[(ct2 * 8 + kb) * 64 + l];
        long b1 = Bshl[((ct2 + 1) * 8 + kb) * 64 + l];
        #pragma unroll
        for (int rt = 0; rt < 4; rt++) {
          acc[0][rt] = __builtin_amdgcn_mfma_f32_16x16x32_bf8_bf8(a[rt][kb], b0, acc[0][rt], 0, 0, 0);
          acc[1][rt] = __builtin_amdgcn_mfma_f32_16x16x32_bf8_bf8(a[rt][kb], b1, acc[1][rt], 0, 0, 0);
        }
      }
      #pragma unroll
      for (int u = 0; u < 2; u++) {
        int col = (c * 4 + ct2 + u) * 16 + lo;
        float bc = b2[col];
        float p = 0.f;
        #pragma unroll
        for (int rt = 0; rt < 4; rt++)
          #pragma unroll
          for (int i = 0; i < 4; i++)
            p = fmaf(w4[rt][i], fmaxf(acc[u][rt][i] + bc, 0.f), p);
        p += __shfl_xor(p, 16);
        p += __shfl_xor(p, 32);
        if (hi == 0) vsh[wv][col] = p;
      }
    }
    __syncthreads();
  }
  float s = vsh[0][t] + vsh[1][t] + vsh[2][t] + vsh[3][t];
  part[(size_t)blockIdx.x * HID + t] = s;
}

// ---------------- K10b: parallel partial reduce part[P][256] -> part2[VRB][256] --------
__global__ __launch_bounds__(256) void k_vred(const float* __restrict__ part, int P,
                                              float* __restrict__ part2) {
  int b = blockIdx.x, t = threadIdx.x;
  int chunk = (P + VRB - 1) / VRB;
  int lo = b * chunk, hi = min(P, lo + chunk);
  float s0 = 0.f, s1 = 0.f, s2 = 0.f, s3 = 0.f;
  int p = lo;
  for (; p + 3 < hi; p += 4) {
    s0 += part[(size_t)p * HID + t];
    s1 += part[(size_t)(p + 1) * HID + t];
    s2 += part[(size_t)(p + 2) * HID + t];
    s3 += part[(size_t)(p + 3) * HID + t];
  }
  for (; p < hi; p++) s0 += part[(size_t)p * HID + t];
  part2[(size_t)b * HID + t] = (s0 + s1) + (s2 + s3);
}

// ---------------- K11: v+gfeat reduce, embedding, MLP head, final transform ------------
__global__ __launch_bounds__(256) void k_head(const float* __restrict__ part2,
                                              const float* __restrict__ gpart, int NG,
                                              const float* __restrict__ W3,
                                              const float* __restrict__ b3,
                                              const float* __restrict__ Wp1,
                                              const float* __restrict__ bp1,
                                              const float* __restrict__ Wp2,
                                              const float* __restrict__ bp2,
                                              const float* __restrict__ Wp3,
                                              const float* __restrict__ bp3,
                                              float* __restrict__ out, int N) {
  __shared__ float vsh[HID];
  __shared__ float gred[256];
  __shared__ float gsh[8];
  __shared__ float emb2[256];
  __shared__ float emb[EMBD + 7];
  __shared__ float h64[64];
  __shared__ float h32[32];
  __shared__ float val[4];
  int t = threadIdx.x;
  {
    float s0 = 0.f, s1 = 0.f, s2 = 0.f, s3 = 0.f;
    #pragma unroll
    for (int p = 0; p < VRB; p += 4) {
      s0 += part2[(size_t)p * HID + t];
      s1 += part2[(size_t)(p + 1) * HID + t];
      s2 += part2[(size_t)(p + 2) * HID + t];
      s3 += part2[(size_t)(p + 3) * HID + t];
    }
    vsh[t] = (s0 + s1) + (s2 + s3);
  }
  {
    float g = 0.f;
    int j = t & 7;
    for (int p = t >> 3; p < NG; p += 32) g += gpart[(size_t)p * 8 + j];
    gred[t] = g;
  }
  __syncthreads();
  if (t < 8) {
    float tot = 0.f;
    for (int q = t; q < 256; q += 8) tot += gred[q];
    gsh[t] = tot;
  }
  // W3 matvec with all 256 threads: 2 threads per output dim
  {
    int dim = t & 127, ch = (t >> 7) * 128;
    float a0 = 0.f, a1 = 0.f, a2 = 0.f, a3 = 0.f;
    #pragma unroll 4
    for (int c = 0; c < 128; c += 4) {
      a0 = fmaf(vsh[ch + c + 0], W3[(size_t)(ch + c + 0) * EMBD + dim], a0);
      a1 = fmaf(vsh[ch + c + 1], W3[(size_t)(ch + c + 1) * EMBD + dim], a1);
      a2 = fmaf(vsh[ch + c + 2], W3[(size_t)(ch + c + 2) * EMBD + dim], a2);
      a3 = fmaf(vsh[ch + c + 3], W3[(size_t)(ch + c + 3) * EMBD + dim], a3);
    }
    emb2[t] = (a0 + a1) + (a2 + a3);
  }
  __syncthreads();
  if (t < EMBD) {
    emb[t] = (emb2[t] + emb2[t + 128]) / (float)N + b3[t];
  } else if (t == EMBD) {
    emb[EMBD + 0] = gsh[0];
    emb[EMBD + 1] = gsh[1];
    emb[EMBD + 2] = gsh[2];
    emb[EMBD + 3] = gsh[1] + gsh[2];
    float cnt = gsh[3];
    emb[EMBD + 4] = cnt > 0.f ? gsh[4] / fmaxf(cnt, 1.f) : 0.f;
    emb[EMBD + 5] = cnt > 0.f ? gsh[5] / fmaxf(cnt, 1.f) : 0.f;
    emb[EMBD + 6] = 100.0f / 500.0f;  // T_norm
  }
  __syncthreads();
  if (t < 64) {
    float a = bp1[t];
    for (int k = 0; k < EMBD + 7; k++) a = fmaf(emb[k], Wp1[k * 64 + t], a);
    h64[t] = fmaxf(a, 0.f);
  }
  __syncthreads();
  if (t < 32) {
    float a = bp2[t];
    for (int k = 0; k < 64; k++) a = fmaf(h64[k], Wp2[k * 32 + t], a);
    h32[t] = fmaxf(a, 0.f);
  }
  __syncthreads();
  if (t < 4) {
    float a = bp3[t];
    for (int k = 0; k < 32; k++) a = fmaf(h32[k], Wp3[k * 4 + t], a);
    val[t] = a > 20.f ? a : log1pf(expf(a));  // softplus
  }
  __syncthreads();
  if (t == 0) {
    const float Tn = 100.0f / 500.0f;
    const float scale = 1.0f - 0.7f * Tn;
    float am = 1.0f + val[0] * scale;
    float aM = 1.0f + (val[0] + val[1] + 1.0f) * scale;
    float bm = 1.0f + val[2] * scale * 0.3f;
    float bM = bm + (val[3] + 0.1f) * scale * 0.3f;
    out[0] = am; out[1] = aM; out[2] = bm; out[3] = bM;
  }
  if (t < EMBD + 7) out[4 + t] = emb[t];
}

static inline size_t al4(size_t a) { return (a + 3) & ~(size_t)3; }

extern "C" void kernel_launch(void* const* d_in, const int* in_sizes, int n_in,
                              void* d_out, int out_size, void* d_ws, size_t ws_size,
                              hipStream_t stream) {
  const float* x = (const float*)d_in[0];
  const int* ei = (const int*)d_in[1];
  const float* W1 = (const float*)d_in[2];
  const float* b1 = (const float*)d_in[3];
  const float* W2 = (const float*)d_in[4];
  const float* b2 = (const float*)d_in[5];
  const float* W3 = (const float*)d_in[6];
  const float* b3 = (const float*)d_in[7];
  const float* Wp1 = (const float*)d_in[8];
  const float* bp1 = (const float*)d_in[9];
  const float* Wp2 = (const float*)d_in[10];
  const float* bp2 = (const float*)d_in[11];
  const float* Wp3 = (const float*)d_in[12];
  const float* bp3 = (const float*)d_in[13];

  int N = in_sizes[0] / FIN;
  int E = in_sizes[1] / 2;
  int nb = (N + 255) / 256;
  int Npad = ((N + 255) / 256) * 256;   // multiple of 256
  int P = Npad / 256;                   // gemm2 blocks / partials
  int NB = (N + BKT - 1) / BKT;         // buckets of 512 nodes
  int per = (E + NBLK - 1) / NBLK;      // edges per hist/place block
  size_t shbytes = (size_t)2 * NB * sizeof(int);

  float* ws = (float*)d_ws;
  size_t o_row  = 0;                                 // N+1 ints
  size_t o_inv  = al4(o_row + N + 1);                // N floats
  size_t o_w    = al4(o_inv + N);                    // N floats
  size_t o_part = al4(o_w + N);                      // P*256 floats
  size_t o_p2   = o_part + (size_t)P * HID;          // VRB*256 floats
  size_t o_gp   = o_p2 + (size_t)VRB * HID;          // NB*8 floats (gfeat partials)
  size_t o_xi   = al4(o_gp + (size_t)NB * 8);        // 4N (uint4/node)
  size_t o_w2t  = o_xi + (size_t)N * 4;              // 16384 floats (HID*HID bf8)
  size_t o_h2dD = o_w2t + (size_t)HID * HID / 4;     // NBLK*NB ints
  size_t o_h2dS = o_h2dD + (size_t)NBLK * NB;        // NBLK*NB ints
  size_t o_btot = o_h2dS + (size_t)NBLK * NB;        // 2*NB
  size_t o_bsD  = o_btot + (size_t)2 * NB;           // NB+1
  size_t o_bsS  = o_bsD + NB + 1;                    // NB+1
  size_t o_seD  = al4(o_bsS + NB + 1);               // E uints
  size_t o_seS  = o_seD + E;                         // E uints
  size_t o_csr  = o_seS + E;                         // E ints
  size_t o_H1q  = al4(o_csr + E);                    // N x 256 B (fp8 rows)
  size_t o_Z    = o_H1q + (size_t)N * (HID / 4);     // Npad x 256 B (bf8 rows)
  size_t total  = o_Z + (size_t)Npad * (HID / 4);
  if (ws_size < total * sizeof(float)) {
    hipMemsetAsync(d_out, 0x42, (size_t)out_size * sizeof(float), stream);
    return;
  }

  int* row = (int*)(ws + o_row);
  int* h2dD = (int*)(ws + o_h2dD);
  int* h2dS = (int*)(ws + o_h2dS);
  int* btot = (int*)(ws + o_btot);
  int* bsD = (int*)(ws + o_bsD);
  int* bsS = (int*)(ws + o_bsS);
  unsigned int* seD = (unsigned int*)(ws + o_seD);
  unsigned int* seS = (unsigned int*)(ws + o_seS);
  int* csr = (int*)(ws + o_csr);
  unsigned char* W2f8 = (unsigned char*)(ws + o_w2t);
  uint4* xi = (uint4*)(ws + o_xi);
  unsigned char* H1q = (unsigned char*)(ws + o_H1q);
  unsigned char* Zq = (unsigned char*)(ws + o_Z);

  k_hist<<<NBLK + HID, 256, shbytes, stream>>>(ei, W2, h2dD, h2dS, W2f8, E, NB, per);
  k_bred<<<2 * NB, 256, 0, stream>>>(h2dD, h2dS, btot, NB);
  k_bscan<<<1, 256, 0, stream>>>(btot, bsD, bsS, row, E, NB, N);
  k_place<<<NBLK, 256, shbytes, stream>>>(ei, h2dD, h2dS, bsD, bsS, seD, seS, E, NB, per);
  k_csrd<<<NB, 256, 0, stream>>>(seD, bsD, x, csr, row, ws + o_inv, xi, ws + o_gp, NB, N);
  k_csrs<<<NB, 256, 0, stream>>>(seS, bsS, ws + o_inv, ws + o_w, NB, N);
  k_h1f<<<nb, 256, 0, stream>>>(xi, row, csr, ws + o_inv, W1, b1, H1q, ws + o_w, N);
  k_agg<<<Npad / 4, 256, 0, stream>>>(row, csr, ws + o_inv, H1q, Zq, N);
  k_gemm2<<<P, 256, 0, stream>>>(Zq, ws + o_w, W2f8, b2, ws + o_part, N);
  k_vred<<<VRB, 256, 0, stream>>>(ws + o_part, P, ws + o_p2);
  k_head<<<1, 256, 0, stream>>>(ws + o_p2, ws + o_gp, NB, W3, b3, Wp1, bp1, Wp2, bp2,
                                Wp3, bp3, (float*)d_out, N);
}